// Round 1
// baseline (531.508 us; speedup 1.0000x reference)
//
#include <hip/hip_runtime.h>
#include <math.h>

#define D 32
#define NSLICE 8

// ---------------- K1: x_n = x / max(||x||, 1e-8) ----------------
__global__ void k_normalize(const float* __restrict__ x, float* __restrict__ xn, int N) {
    int g = blockIdx.x * blockDim.x + threadIdx.x;   // N*8 threads, 8 lanes/sample
    int i = g >> 3, q = g & 7;
    if (i >= N) return;
    float4 v = ((const float4*)(x + (size_t)i * D))[q];
    float ss = v.x*v.x + v.y*v.y + v.z*v.z + v.w*v.w;
    ss += __shfl_xor(ss, 1);
    ss += __shfl_xor(ss, 2);
    ss += __shfl_xor(ss, 4);
    float nrm = fmaxf(sqrtf(ss), 1e-8f);
    float4 o; o.x = v.x/nrm; o.y = v.y/nrm; o.z = v.z/nrm; o.w = v.w/nrm;
    ((float4*)(xn + (size_t)i * D))[q] = o;
}

// ---------------- K2: per-class sequential EMA chain (wave per class) ------
// Also emits q[c][:] = relu(kappa[c]) * p_n[c][:] and logw[c].
__global__ void k_proto(const float* __restrict__ x, const int* __restrict__ tgt,
                        const float* __restrict__ p_in, const float* __restrict__ kw,
                        float* __restrict__ qout, float* __restrict__ logw,
                        int N, int C, float dval) {
    int wave = (blockIdx.x * blockDim.x + threadIdx.x) >> 6;
    int lane = threadIdx.x & 63;
    if (wave >= C) return;
    int c = wave, e = lane & 31;           // lanes 32-63 mirror lanes 0-31
    float p = p_in[(size_t)c * D + e];
    for (int ii = 0; ii < N; ii += 64) {
        unsigned long long m = __ballot(tgt[ii + lane] == c);
        while (m) {                         // m is wave-uniform
            int j = __ffsll(m) - 1;
            m &= (m - 1);
            int idx = ii + j;
            float s = x[(size_t)idx * D + e];
            float ss = s * s;               // normalize sample (eps 1e-12)
            ss += __shfl_xor(ss, 16); ss += __shfl_xor(ss, 8); ss += __shfl_xor(ss, 4);
            ss += __shfl_xor(ss, 2);  ss += __shfl_xor(ss, 1);
            s = s / fmaxf(sqrtf(ss), 1e-12f);
            p = 0.05f * s + 0.95f * p;
            float pp = p * p;               // renormalize proto (eps 1e-12)
            pp += __shfl_xor(pp, 16); pp += __shfl_xor(pp, 8); pp += __shfl_xor(pp, 4);
            pp += __shfl_xor(pp, 2);  pp += __shfl_xor(pp, 1);
            p = p / fmaxf(sqrtf(pp), 1e-12f);
        }
    }
    // cosine-normalize (eps 1e-8) and fold kappa in
    float pp = p * p;
    pp += __shfl_xor(pp, 16); pp += __shfl_xor(pp, 8); pp += __shfl_xor(pp, 4);
    pp += __shfl_xor(pp, 2);  pp += __shfl_xor(pp, 1);
    float pn = p / fmaxf(sqrtf(pp), 1e-8f);
    float kap = fmaxf(kw[c], 0.0f);
    if (lane < D) qout[(size_t)c * D + e] = kap * pn;
    if (lane == 0) {
        // log C_d(kap), cancellation-free rearrangement of the reference formula:
        // s*log(k) - nu*eta = nu*(log(nu) + log1p(sq) - sq)
        float nu = 0.5f * dval - 1.0f;
        float z  = kap / nu, z2 = z * z;
        float sq = sqrtf(1.0f + z2);
        float t  = 1.0f / sq;
        float u1 = (3.0f * t - 5.0f * t * t * t) * (1.0f / 24.0f);
        logw[c] = dval * (-0.918938533204672742f)
                + nu * (logf(nu) + log1pf(sq) - sq)
                + 0.5f * logf(6.2831853071795864f * nu)
                + 0.25f * log1pf(z2)
                - log1pf(u1 / nu);
    }
}

// ---------------- K3: fused logits+exp+partial-rowsum over a class slice ---
__global__ void k_slice(const float* __restrict__ xn, const int* __restrict__ tgt,
                        const float* __restrict__ q, const float* __restrict__ logw,
                        float* __restrict__ Sp, float* __restrict__ ltw,
                        int N, int C) {
    int g = blockIdx.x * blockDim.x + threadIdx.x;   // N * NSLICE threads
    int i = g >> 3, sl = g & (NSLICE - 1);
    if (i >= N) return;
    float xr[D];
#pragma unroll
    for (int k = 0; k < D / 4; ++k) {
        float4 v = ((const float4*)(xn + (size_t)i * D))[k];
        xr[4*k] = v.x; xr[4*k+1] = v.y; xr[4*k+2] = v.z; xr[4*k+3] = v.w;
    }
    int t = tgt[i];
    int cs = C / NSLICE;
    int c0 = sl * cs, c1 = c0 + cs;
    float S = 0.0f, lt = 0.0f;
    for (int c = c0; c < c1; ++c) {
        const float4* qv = (const float4*)(q + (size_t)c * D);  // wave-uniform address
        float a0 = 0.f, a1 = 0.f, a2 = 0.f, a3 = 0.f;
#pragma unroll
        for (int k = 0; k < D / 4; ++k) {
            float4 w = qv[k];
            a0 = fmaf(xr[4*k],   w.x, a0);
            a1 = fmaf(xr[4*k+1], w.y, a1);
            a2 = fmaf(xr[4*k+2], w.z, a2);
            a3 = fmaf(xr[4*k+3], w.w, a3);
        }
        float l = logw[c] + ((a0 + a1) + (a2 + a3));
        S += __expf(l);
        if (c == t) lt = l;
    }
    Sp[g] = S;
    if (t >= c0 && t < c1) ltw[i] = lt;
}

// ---------------- K4: combine slices, per-sample NLL, deterministic mean ---
__global__ void k_final(const float* __restrict__ Sp, const float* __restrict__ ltw,
                        float* __restrict__ out, int N) {
    __shared__ float red[16];
    float acc = 0.0f;
    for (int i = threadIdx.x; i < N; i += blockDim.x) {
        float S = 0.0f;
#pragma unroll
        for (int s = 0; s < NSLICE; ++s) S += Sp[(size_t)i * NSLICE + s];
        float p = __expf(ltw[i]) / S;
        acc += logf(p + 1e-6f);
    }
    for (int o = 32; o >= 1; o >>= 1) acc += __shfl_xor(acc, o);
    int wid = threadIdx.x >> 6;
    if ((threadIdx.x & 63) == 0) red[wid] = acc;
    __syncthreads();
    if (threadIdx.x == 0) {
        float tot = 0.0f;
        int nw = blockDim.x >> 6;
        for (int w = 0; w < nw; ++w) tot += red[w];
        out[0] = -tot / (float)N;
    }
}

extern "C" void kernel_launch(void* const* d_in, const int* in_sizes, int n_in,
                              void* d_out, int out_size, void* d_ws, size_t ws_size,
                              hipStream_t stream) {
    const float* x    = (const float*)d_in[0];   // [N, D]
    const float* kw   = (const float*)d_in[1];   // [C]
    const float* p_in = (const float*)d_in[2];   // [C, D]
    const int*   tgt  = (const int*)d_in[3];     // [N]
    int C = in_sizes[1];
    int Dv = in_sizes[2] / C;                    // == 32
    int N = in_sizes[3];
    float dval = (float)Dv;

    float* ws  = (float*)d_ws;
    float* xn  = ws;                              // N*D
    float* q   = xn + (size_t)N * D;              // C*D
    float* lw  = q + (size_t)C * D;               // C
    float* Sp  = lw + C;                          // N*NSLICE
    float* ltw = Sp + (size_t)N * NSLICE;         // N

    (void)Dv; (void)n_in; (void)out_size; (void)ws_size;

    // K1: normalize samples
    {
        int threads = N * 8;
        k_normalize<<<(threads + 255) / 256, 256, 0, stream>>>(x, xn, N);
    }
    // K2: per-class EMA chains + q/logw
    {
        int threads = C * 64;
        k_proto<<<(threads + 255) / 256, 256, 0, stream>>>(x, tgt, p_in, kw, q, lw, N, C, dval);
    }
    // K3: fused logits + exp + partial sums
    {
        int threads = N * NSLICE;
        k_slice<<<(threads + 255) / 256, 256, 0, stream>>>(xn, tgt, q, lw, Sp, ltw, N, C);
    }
    // K4: final reduction
    k_final<<<1, 1024, 0, stream>>>(Sp, ltw, (float*)d_out, N);
}

// Round 2
// 64.865 us; speedup vs baseline: 8.1940x; 8.1940x over previous
//
#include <hip/hip_runtime.h>
#include <hip/hip_bf16.h>
#include <math.h>

#define D 32
#define NS2 16   // class-tile slices in k_slice

typedef __attribute__((ext_vector_type(8))) short short8v;
typedef __attribute__((ext_vector_type(4))) float float4v;

static __device__ __forceinline__ unsigned short f2bf(float f) {
    union { __hip_bfloat16 h; unsigned short u; } cv;
    cv.h = __float2bfloat16(f);
    return cv.u;
}
static __device__ __forceinline__ float bf2f(unsigned short u) {
    union { float f; unsigned int i; } c;
    c.i = ((unsigned int)u) << 16;
    return c.f;
}

// ---------------- K1: xnb = bf16( x / max(||x||,1e-8) ) ----------------
__global__ void k_normalize(const float* __restrict__ x, unsigned short* __restrict__ xnb, int N) {
    int g = blockIdx.x * blockDim.x + threadIdx.x;   // N*8 threads, 8 lanes/sample
    int i = g >> 3, q = g & 7;
    if (i >= N) return;
    float4 v = ((const float4*)(x + (size_t)i * D))[q];
    float ss = v.x*v.x + v.y*v.y + v.z*v.z + v.w*v.w;
    ss += __shfl_xor(ss, 1); ss += __shfl_xor(ss, 2); ss += __shfl_xor(ss, 4);
    float nrm = fmaxf(sqrtf(ss), 1e-8f);
    ushort4 ob;
    ob.x = f2bf(v.x / nrm); ob.y = f2bf(v.y / nrm);
    ob.z = f2bf(v.z / nrm); ob.w = f2bf(v.w / nrm);
    ((ushort4*)(xnb + (size_t)i * D))[q] = ob;
}

// ---------------- K2: per-class EMA chain -> qb (bf16, kappa folded), w=exp(logw) ----
__global__ void k_proto(const unsigned short* __restrict__ xnb, const int* __restrict__ tgt,
                        const float* __restrict__ p_in, const float* __restrict__ kw,
                        unsigned short* __restrict__ qb, float* __restrict__ w,
                        int N, int C, float dval) {
    int wave = (blockIdx.x * blockDim.x + threadIdx.x) >> 6;
    int lane = threadIdx.x & 63;
    if (wave >= C) return;
    int c = wave, e = lane & 31;           // lanes 32-63 mirror lanes 0-31
    float p = p_in[(size_t)c * D + e];
    for (int ii = 0; ii < N; ii += 64) {
        unsigned long long m = __ballot(tgt[ii + lane] == c);
        while (m) {                         // wave-uniform
            int j = __ffsll(m) - 1;
            m &= (m - 1);
            float s = bf2f(xnb[(size_t)(ii + j) * D + e]);   // pre-normalized sample
            p = fmaf(0.05f, s, 0.95f * p);
            float pp = p * p;               // renormalize proto
            pp += __shfl_xor(pp, 16); pp += __shfl_xor(pp, 8); pp += __shfl_xor(pp, 4);
            pp += __shfl_xor(pp, 2);  pp += __shfl_xor(pp, 1);
            p = p / fmaxf(sqrtf(pp), 1e-12f);
        }
    }
    float pp = p * p;
    pp += __shfl_xor(pp, 16); pp += __shfl_xor(pp, 8); pp += __shfl_xor(pp, 4);
    pp += __shfl_xor(pp, 2);  pp += __shfl_xor(pp, 1);
    float pn = p / fmaxf(sqrtf(pp), 1e-8f);
    float kap = fmaxf(kw[c], 0.0f);
    if (lane < D) qb[(size_t)c * D + e] = f2bf(kap * pn);
    if (lane == 0) {
        // log C_d(kap), cancellation-free rearrangement
        float nu = 0.5f * dval - 1.0f;
        float z  = kap / nu, z2 = z * z;
        float sq = sqrtf(1.0f + z2);
        float t  = 1.0f / sq;
        float u1 = (3.0f * t - 5.0f * t * t * t) * (1.0f / 24.0f);
        float lw = dval * (-0.918938533204672742f)
                 + nu * (logf(nu) + log1pf(sq) - sq)
                 + 0.5f * logf(6.2831853071795864f * nu)
                 + 0.25f * log1pf(z2)
                 - log1pf(u1 / nu);
        w[c] = __expf(lw);
    }
}

// ---------------- K3: MFMA cos -> fused w*exp -> per-sample partial row-sums ----
// wave: 2 sample-tiles (32 samples) x 8 class-tiles (128 classes of slice sl)
__global__ void __launch_bounds__(256, 8)
k_slice(const unsigned short* __restrict__ xnb, const unsigned short* __restrict__ qb,
        const float* __restrict__ w, float* __restrict__ Sp, int N, int C) {
    int gw = (blockIdx.x * blockDim.x + threadIdx.x) >> 6;   // 8192 waves
    int lane = threadIdx.x & 63;
    int sl = gw >> 9;          // 0..15  (class slice)
    int sw = gw & 511;         // 0..511 (sample group of 32)
    int s0 = sw * 32;
    int m = lane & 15, kg = lane >> 4, k0 = kg * 8;

    // A fragments: A[m=lane&15][k = (lane>>4)*8 + j] -> 16B contiguous per lane
    short8v a0 = *(const short8v*)(xnb + (size_t)(s0 + m) * D + k0);
    short8v a1 = *(const short8v*)(xnb + (size_t)(s0 + 16 + m) * D + k0);

    float4v z = {0.f, 0.f, 0.f, 0.f};
    float4v sa0 = z, sa1 = z;
    int ctbase = sl * 8;
#pragma unroll
    for (int j = 0; j < 8; ++j) {
        int c0 = (ctbase + j) * 16;
        // B fragment: B[k][n=lane&15] from row-major qb[class][k] -> 16B per lane
        short8v b = *(const short8v*)(qb + (size_t)(c0 + m) * D + k0);
        float wl = w[c0 + m];
        float4v acc0 = __builtin_amdgcn_mfma_f32_16x16x32_bf16(a0, b, z, 0, 0, 0);
        float4v acc1 = __builtin_amdgcn_mfma_f32_16x16x32_bf16(a1, b, z, 0, 0, 0);
#pragma unroll
        for (int r = 0; r < 4; ++r) {
            sa0[r] = fmaf(wl, __expf(acc0[r]), sa0[r]);
            sa1[r] = fmaf(wl, __expf(acc1[r]), sa1[r]);
        }
    }
    // reduce across the 16 class-columns (lanes sharing kg group)
#pragma unroll
    for (int off = 1; off < 16; off <<= 1) {
#pragma unroll
        for (int r = 0; r < 4; ++r) {
            sa0[r] += __shfl_xor(sa0[r], off);
            sa1[r] += __shfl_xor(sa1[r], off);
        }
    }
    if (m == 0) {
#pragma unroll
        for (int r = 0; r < 4; ++r) {
            int sA = s0 + kg * 4 + r;            // C/D: row = (lane>>4)*4 + r
            Sp[(size_t)sA * NS2 + sl] = sa0[r];
            Sp[(size_t)(sA + 16) * NS2 + sl] = sa1[r];
        }
    }
}

// ---------------- K4a: per-sample NLL + per-block partial sums ----------------
__global__ void k_nll(const unsigned short* __restrict__ xnb, const unsigned short* __restrict__ qb,
                      const int* __restrict__ tgt, const float* __restrict__ w,
                      const float* __restrict__ Sp, float* __restrict__ part, int N) {
    int i = blockIdx.x * blockDim.x + threadIdx.x;
    float val = 0.0f;
    if (i < N) {
        float S = 0.f;
        const float4* sp = (const float4*)(Sp + (size_t)i * NS2);
#pragma unroll
        for (int j = 0; j < NS2 / 4; ++j) { float4 v = sp[j]; S += (v.x + v.y) + (v.z + v.w); }
        int t = tgt[i];
        float d = 0.f;
        const ushort4* xa = (const ushort4*)(xnb + (size_t)i * D);
        const ushort4* qa = (const ushort4*)(qb + (size_t)t * D);
#pragma unroll
        for (int j = 0; j < D / 4; ++j) {
            ushort4 xv = xa[j], qv = qa[j];
            d = fmaf(bf2f(xv.x), bf2f(qv.x), d);
            d = fmaf(bf2f(xv.y), bf2f(qv.y), d);
            d = fmaf(bf2f(xv.z), bf2f(qv.z), d);
            d = fmaf(bf2f(xv.w), bf2f(qv.w), d);
        }
        float num = w[t] * __expf(d);
        val = logf(num / S + 1e-6f);
    }
    __shared__ float red[4];
    val += __shfl_xor(val, 32); val += __shfl_xor(val, 16); val += __shfl_xor(val, 8);
    val += __shfl_xor(val, 4);  val += __shfl_xor(val, 2);  val += __shfl_xor(val, 1);
    if ((threadIdx.x & 63) == 0) red[threadIdx.x >> 6] = val;
    __syncthreads();
    if (threadIdx.x == 0) part[blockIdx.x] = (red[0] + red[1]) + (red[2] + red[3]);
}

// ---------------- K4b: final 64-element reduce ----------------
__global__ void k_out(const float* __restrict__ part, float* __restrict__ out, int N) {
    float v = part[threadIdx.x];
    v += __shfl_xor(v, 32); v += __shfl_xor(v, 16); v += __shfl_xor(v, 8);
    v += __shfl_xor(v, 4);  v += __shfl_xor(v, 2);  v += __shfl_xor(v, 1);
    if (threadIdx.x == 0) out[0] = -v / (float)N;
}

extern "C" void kernel_launch(void* const* d_in, const int* in_sizes, int n_in,
                              void* d_out, int out_size, void* d_ws, size_t ws_size,
                              hipStream_t stream) {
    const float* x    = (const float*)d_in[0];   // [N, D]
    const float* kw   = (const float*)d_in[1];   // [C]
    const float* p_in = (const float*)d_in[2];   // [C, D]
    const int*   tgt  = (const int*)d_in[3];     // [N]
    int C = in_sizes[1];
    int N = in_sizes[3];
    float dval = (float)(in_sizes[2] / C);       // == 32

    unsigned short* xnb = (unsigned short*)d_ws;           // N*D bf16  (1 MB)
    unsigned short* qb  = xnb + (size_t)N * D;             // C*D bf16  (128 KB)
    float* w    = (float*)(qb + (size_t)C * D);            // C f32
    float* Sp   = w + C;                                   // N*NS2 f32 (1 MB)
    float* part = Sp + (size_t)N * NS2;                    // 64 f32
    (void)n_in; (void)out_size; (void)ws_size;

    // K1: normalize + bf16
    k_normalize<<<(N * 8 + 255) / 256, 256, 0, stream>>>(x, xnb, N);
    // K2: per-class EMA chains -> qb, w
    k_proto<<<(C * 64 + 255) / 256, 256, 0, stream>>>(xnb, tgt, p_in, kw, qb, w, N, C, dval);
    // K3: MFMA + fused exp/rowsum partials  (8192 waves)
    {
        int waves = (N / 32) * NS2;
        k_slice<<<waves / 4, 256, 0, stream>>>(xnb, qb, w, Sp, N, C);
    }
    // K4: per-sample NLL + block partials, then final reduce
    k_nll<<<N / 256, 256, 0, stream>>>(xnb, qb, tgt, w, Sp, part, N);
    k_out<<<1, 64, 0, stream>>>(part, (float*)d_out, N);
}

// Round 3
// 53.782 us; speedup vs baseline: 9.8827x; 1.2061x over previous
//
#include <hip/hip_runtime.h>
#include <hip/hip_bf16.h>
#include <math.h>

#define D 32
#define NS2 16   // class-tile slices in k_slice

typedef __attribute__((ext_vector_type(8))) short short8v;
typedef __attribute__((ext_vector_type(4))) float float4v;

static __device__ __forceinline__ unsigned short f2bf(float f) {
    union { __hip_bfloat16 h; unsigned short u; } cv;
    cv.h = __float2bfloat16(f);
    return cv.u;
}
static __device__ __forceinline__ float bf2f(unsigned short u) {
    union { float f; unsigned int i; } c;
    c.i = ((unsigned int)u) << 16;
    return c.f;
}

// ---------------- K1: xnb = bf16( x / max(||x||,1e-8) ) ----------------
__global__ void k_normalize(const float* __restrict__ x, unsigned short* __restrict__ xnb, int N) {
    int g = blockIdx.x * blockDim.x + threadIdx.x;   // N*8 threads, 8 lanes/sample
    int i = g >> 3, q = g & 7;
    if (i >= N) return;
    float4 v = ((const float4*)(x + (size_t)i * D))[q];
    float ss = v.x*v.x + v.y*v.y + v.z*v.z + v.w*v.w;
    ss += __shfl_xor(ss, 1); ss += __shfl_xor(ss, 2); ss += __shfl_xor(ss, 4);
    float nrm = fmaxf(sqrtf(ss), 1e-8f);
    ushort4 ob;
    ob.x = f2bf(v.x / nrm); ob.y = f2bf(v.y / nrm);
    ob.z = f2bf(v.z / nrm); ob.w = f2bf(v.w / nrm);
    ((ushort4*)(xnb + (size_t)i * D))[q] = ob;
}

// ---------------- K_bucket: counting-sort targets into per-class lists ----
// Single block, 1024 threads. LDS: A[C+1], B[C+1] ping-pong (16.4 KB at C=2048).
__global__ void k_bucket(const int* __restrict__ tgt, int* __restrict__ list,
                         int* __restrict__ offs, int N, int C) {
    extern __shared__ int lds[];
    int* A = lds;            // C+1
    int* B = lds + C + 1;    // C+1
    int tid = threadIdx.x, nth = blockDim.x;
    for (int c = tid; c < C; c += nth) A[c] = 0;
    __syncthreads();
    for (int i = tid; i < N; i += nth) atomicAdd(&A[tgt[i]], 1);
    __syncthreads();
    // inclusive Hillis-Steele scan over C entries (ping-pong A<->B)
    int* src = A; int* dst = B;
    for (int off = 1; off < C; off <<= 1) {
        for (int c = tid; c < C; c += nth) {
            int v = src[c];
            if (c >= off) v += src[c - off];
            dst[c] = v;
        }
        __syncthreads();
        int* t = src; src = dst; dst = t;
    }
    // exclusive offsets -> global offs[0..C]; dst[] becomes running positions
    for (int c = tid; c <= C; c += nth) {
        int v = (c == 0) ? 0 : src[c - 1];
        offs[c] = v;
        if (c < C) dst[c] = v;
    }
    __syncthreads();
    // scatter (order within a class is arbitrary; k_proto re-sorts by index)
    for (int i = tid; i < N; i += nth) {
        int slot = atomicAdd(&dst[tgt[i]], 1);
        list[slot] = i;
    }
}

// ---------------- K2: per-class EMA chain -> qb (bf16, kappa folded), w ----
__global__ void k_proto(const unsigned short* __restrict__ xnb, const int* __restrict__ tgt,
                        const int* __restrict__ list, const int* __restrict__ offs,
                        const float* __restrict__ p_in, const float* __restrict__ kw,
                        unsigned short* __restrict__ qb, float* __restrict__ w,
                        int N, int C, float dval) {
    int wave = (blockIdx.x * blockDim.x + threadIdx.x) >> 6;
    int lane = threadIdx.x & 63;
    if (wave >= C) return;
    int c = wave, e = lane & 31;           // lanes 32-63 mirror lanes 0-31
    float p = p_in[(size_t)c * D + e];
    int base = offs[c];
    int count = offs[c + 1] - base;

    if (count <= 64) {
        // lane l holds l-th (unordered) sample index; process in ascending order
        int idx = (lane < count) ? list[base + lane] : 0x7fffffff;
        for (int it = 0; it < count; ++it) {
            int mn = idx;
            mn = min(mn, __shfl_xor(mn, 32)); mn = min(mn, __shfl_xor(mn, 16));
            mn = min(mn, __shfl_xor(mn, 8));  mn = min(mn, __shfl_xor(mn, 4));
            mn = min(mn, __shfl_xor(mn, 2));  mn = min(mn, __shfl_xor(mn, 1));
            float s = bf2f(xnb[(size_t)mn * D + e]);
            p = fmaf(0.05f, s, 0.95f * p);
            float pp = p * p;
            pp += __shfl_xor(pp, 16); pp += __shfl_xor(pp, 8); pp += __shfl_xor(pp, 4);
            pp += __shfl_xor(pp, 2);  pp += __shfl_xor(pp, 1);
            p = p / fmaxf(sqrtf(pp), 1e-12f);
            if (idx == mn) idx = 0x7fffffff;
        }
    } else {
        // fallback (statistically never at N/C=8): original full ballot scan
        for (int ii = 0; ii < N; ii += 64) {
            unsigned long long m = __ballot(tgt[ii + lane] == c);
            while (m) {
                int j = __ffsll(m) - 1;
                m &= (m - 1);
                float s = bf2f(xnb[(size_t)(ii + j) * D + e]);
                p = fmaf(0.05f, s, 0.95f * p);
                float pp = p * p;
                pp += __shfl_xor(pp, 16); pp += __shfl_xor(pp, 8); pp += __shfl_xor(pp, 4);
                pp += __shfl_xor(pp, 2);  pp += __shfl_xor(pp, 1);
                p = p / fmaxf(sqrtf(pp), 1e-12f);
            }
        }
    }

    float pp = p * p;
    pp += __shfl_xor(pp, 16); pp += __shfl_xor(pp, 8); pp += __shfl_xor(pp, 4);
    pp += __shfl_xor(pp, 2);  pp += __shfl_xor(pp, 1);
    float pn = p / fmaxf(sqrtf(pp), 1e-8f);
    float kap = fmaxf(kw[c], 0.0f);
    if (lane < D) qb[(size_t)c * D + e] = f2bf(kap * pn);
    if (lane == 0) {
        // log C_d(kap), cancellation-free rearrangement
        float nu = 0.5f * dval - 1.0f;
        float z  = kap / nu, z2 = z * z;
        float sq = sqrtf(1.0f + z2);
        float t  = 1.0f / sq;
        float u1 = (3.0f * t - 5.0f * t * t * t) * (1.0f / 24.0f);
        float lw = dval * (-0.918938533204672742f)
                 + nu * (logf(nu) + log1pf(sq) - sq)
                 + 0.5f * logf(6.2831853071795864f * nu)
                 + 0.25f * log1pf(z2)
                 - log1pf(u1 / nu);
        w[c] = __expf(lw);
    }
}

// ---------------- K3: MFMA cos -> fused w*exp -> per-sample partial row-sums ----
__global__ void __launch_bounds__(256, 8)
k_slice(const unsigned short* __restrict__ xnb, const unsigned short* __restrict__ qb,
        const float* __restrict__ w, float* __restrict__ Sp, int N, int C) {
    int gw = (blockIdx.x * blockDim.x + threadIdx.x) >> 6;   // 8192 waves
    int lane = threadIdx.x & 63;
    int sl = gw >> 9;          // 0..15  (class slice)
    int sw = gw & 511;         // 0..511 (sample group of 32)
    int s0 = sw * 32;
    int m = lane & 15, kg = lane >> 4, k0 = kg * 8;

    short8v a0 = *(const short8v*)(xnb + (size_t)(s0 + m) * D + k0);
    short8v a1 = *(const short8v*)(xnb + (size_t)(s0 + 16 + m) * D + k0);

    float4v z = {0.f, 0.f, 0.f, 0.f};
    float4v sa0 = z, sa1 = z;
    int ctbase = sl * 8;
#pragma unroll
    for (int j = 0; j < 8; ++j) {
        int c0 = (ctbase + j) * 16;
        short8v b = *(const short8v*)(qb + (size_t)(c0 + m) * D + k0);
        float wl = w[c0 + m];
        float4v acc0 = __builtin_amdgcn_mfma_f32_16x16x32_bf16(a0, b, z, 0, 0, 0);
        float4v acc1 = __builtin_amdgcn_mfma_f32_16x16x32_bf16(a1, b, z, 0, 0, 0);
#pragma unroll
        for (int r = 0; r < 4; ++r) {
            sa0[r] = fmaf(wl, __expf(acc0[r]), sa0[r]);
            sa1[r] = fmaf(wl, __expf(acc1[r]), sa1[r]);
        }
    }
#pragma unroll
    for (int off = 1; off < 16; off <<= 1) {
#pragma unroll
        for (int r = 0; r < 4; ++r) {
            sa0[r] += __shfl_xor(sa0[r], off);
            sa1[r] += __shfl_xor(sa1[r], off);
        }
    }
    if (m == 0) {
#pragma unroll
        for (int r = 0; r < 4; ++r) {
            int sA = s0 + kg * 4 + r;
            Sp[(size_t)sA * NS2 + sl] = sa0[r];
            Sp[(size_t)(sA + 16) * NS2 + sl] = sa1[r];
        }
    }
}

// ---------------- K4a: per-sample NLL + per-block partial sums ----------------
__global__ void k_nll(const unsigned short* __restrict__ xnb, const unsigned short* __restrict__ qb,
                      const int* __restrict__ tgt, const float* __restrict__ w,
                      const float* __restrict__ Sp, float* __restrict__ part, int N) {
    int i = blockIdx.x * blockDim.x + threadIdx.x;
    float val = 0.0f;
    if (i < N) {
        float S = 0.f;
        const float4* sp = (const float4*)(Sp + (size_t)i * NS2);
#pragma unroll
        for (int j = 0; j < NS2 / 4; ++j) { float4 v = sp[j]; S += (v.x + v.y) + (v.z + v.w); }
        int t = tgt[i];
        float d = 0.f;
        const ushort4* xa = (const ushort4*)(xnb + (size_t)i * D);
        const ushort4* qa = (const ushort4*)(qb + (size_t)t * D);
#pragma unroll
        for (int j = 0; j < D / 4; ++j) {
            ushort4 xv = xa[j], qv = qa[j];
            d = fmaf(bf2f(xv.x), bf2f(qv.x), d);
            d = fmaf(bf2f(xv.y), bf2f(qv.y), d);
            d = fmaf(bf2f(xv.z), bf2f(qv.z), d);
            d = fmaf(bf2f(xv.w), bf2f(qv.w), d);
        }
        float num = w[t] * __expf(d);
        val = logf(num / S + 1e-6f);
    }
    __shared__ float red[4];
    val += __shfl_xor(val, 32); val += __shfl_xor(val, 16); val += __shfl_xor(val, 8);
    val += __shfl_xor(val, 4);  val += __shfl_xor(val, 2);  val += __shfl_xor(val, 1);
    if ((threadIdx.x & 63) == 0) red[threadIdx.x >> 6] = val;
    __syncthreads();
    if (threadIdx.x == 0) part[blockIdx.x] = (red[0] + red[1]) + (red[2] + red[3]);
}

// ---------------- K4b: final 64-element reduce ----------------
__global__ void k_out(const float* __restrict__ part, float* __restrict__ out, int N) {
    float v = part[threadIdx.x];
    v += __shfl_xor(v, 32); v += __shfl_xor(v, 16); v += __shfl_xor(v, 8);
    v += __shfl_xor(v, 4);  v += __shfl_xor(v, 2);  v += __shfl_xor(v, 1);
    if (threadIdx.x == 0) out[0] = -v / (float)N;
}

extern "C" void kernel_launch(void* const* d_in, const int* in_sizes, int n_in,
                              void* d_out, int out_size, void* d_ws, size_t ws_size,
                              hipStream_t stream) {
    const float* x    = (const float*)d_in[0];   // [N, D]
    const float* kw   = (const float*)d_in[1];   // [C]
    const float* p_in = (const float*)d_in[2];   // [C, D]
    const int*   tgt  = (const int*)d_in[3];     // [N]
    int C = in_sizes[1];
    int N = in_sizes[3];
    float dval = (float)(in_sizes[2] / C);       // == 32

    unsigned short* xnb = (unsigned short*)d_ws;           // N*D bf16  (1 MB)
    unsigned short* qb  = xnb + (size_t)N * D;             // C*D bf16  (128 KB)
    float* w    = (float*)(qb + (size_t)C * D);            // C f32
    float* Sp   = w + C;                                   // N*NS2 f32 (1 MB)
    float* part = Sp + (size_t)N * NS2;                    // 64 f32
    int* list   = (int*)(part + 64);                       // N ints
    int* offs   = list + N;                                // C+1 ints
    (void)n_in; (void)out_size; (void)ws_size;

    // K1: normalize + bf16
    k_normalize<<<(N * 8 + 255) / 256, 256, 0, stream>>>(x, xnb, N);
    // K_bucket: per-class ordered-recoverable sample lists (single block)
    k_bucket<<<1, 1024, 2 * (C + 1) * sizeof(int), stream>>>(tgt, list, offs, N, C);
    // K2: per-class EMA chains -> qb, w
    k_proto<<<(C * 64 + 255) / 256, 256, 0, stream>>>(xnb, tgt, list, offs, p_in, kw, qb, w, N, C, dval);
    // K3: MFMA + fused exp/rowsum partials  (8192 waves)
    {
        int waves = (N / 32) * NS2;
        k_slice<<<waves / 4, 256, 0, stream>>>(xnb, qb, w, Sp, N, C);
    }
    // K4: per-sample NLL + block partials, then final reduce
    k_nll<<<N / 256, 256, 0, stream>>>(xnb, qb, tgt, w, Sp, part, N);
    k_out<<<1, 64, 0, stream>>>(part, (float*)d_out, N);
}

// Round 4
// 44.540 us; speedup vs baseline: 11.9333x; 1.2075x over previous
//
#include <hip/hip_runtime.h>
#include <hip/hip_bf16.h>
#include <math.h>

#define D 32
#define NS2 16   // class-tile slices in k_slice
#define CAP 64   // per-class bucket capacity (fallback to full scan if exceeded)

typedef __attribute__((ext_vector_type(8))) short short8v;
typedef __attribute__((ext_vector_type(4))) float float4v;

static __device__ __forceinline__ unsigned short f2bf(float f) {
    union { __hip_bfloat16 h; unsigned short u; } cv;
    cv.h = __float2bfloat16(f);
    return cv.u;
}
static __device__ __forceinline__ float bf2f(unsigned short u) {
    union { float f; unsigned int i; } c;
    c.i = ((unsigned int)u) << 16;
    return c.f;
}

// ---- K1: xnb = bf16(x/max(||x||,1e-8)) + bucket-scatter sample indices ----
__global__ void k_normalize(const float* __restrict__ x, const int* __restrict__ tgt,
                            unsigned short* __restrict__ xnb,
                            int* __restrict__ cnt, int* __restrict__ list2d, int N) {
    int g = blockIdx.x * blockDim.x + threadIdx.x;   // N*8 threads, 8 lanes/sample
    int i = g >> 3, q = g & 7;
    if (i >= N) return;
    float4 v = ((const float4*)(x + (size_t)i * D))[q];
    float ss = v.x*v.x + v.y*v.y + v.z*v.z + v.w*v.w;
    ss += __shfl_xor(ss, 1); ss += __shfl_xor(ss, 2); ss += __shfl_xor(ss, 4);
    float nrm = fmaxf(sqrtf(ss), 1e-8f);
    ushort4 ob;
    ob.x = f2bf(v.x / nrm); ob.y = f2bf(v.y / nrm);
    ob.z = f2bf(v.z / nrm); ob.w = f2bf(v.w / nrm);
    ((ushort4*)(xnb + (size_t)i * D))[q] = ob;
    if (q == 0) {
        int t = tgt[i];
        int pos = atomicAdd(&cnt[t], 1);
        if (pos < CAP) list2d[t * CAP + pos] = i;   // unordered; k_proto re-sorts
    }
}

// ---- K2: per-class sequential EMA chain -> qb (bf16, kappa folded), w ----
__global__ void k_proto(const unsigned short* __restrict__ xnb, const int* __restrict__ tgt,
                        const int* __restrict__ list2d, const int* __restrict__ cnt,
                        const float* __restrict__ p_in, const float* __restrict__ kw,
                        unsigned short* __restrict__ qb, float* __restrict__ w,
                        int N, int C, float dval) {
    int wave = (blockIdx.x * blockDim.x + threadIdx.x) >> 6;
    int lane = threadIdx.x & 63;
    if (wave >= C) return;
    int c = wave, e = lane & 31;           // lanes 32-63 mirror lanes 0-31
    float p = p_in[(size_t)c * D + e];
    int count = cnt[c];

    if (count <= CAP) {
        // lane l holds l-th (unordered) sample index; process in ascending order
        int idx = (lane < count) ? list2d[c * CAP + lane] : 0x7fffffff;
        for (int it = 0; it < count; ++it) {
            int mn = idx;
            mn = min(mn, __shfl_xor(mn, 32)); mn = min(mn, __shfl_xor(mn, 16));
            mn = min(mn, __shfl_xor(mn, 8));  mn = min(mn, __shfl_xor(mn, 4));
            mn = min(mn, __shfl_xor(mn, 2));  mn = min(mn, __shfl_xor(mn, 1));
            float s = bf2f(xnb[(size_t)mn * D + e]);
            p = fmaf(0.05f, s, 0.95f * p);
            float pp = p * p;
            pp += __shfl_xor(pp, 16); pp += __shfl_xor(pp, 8); pp += __shfl_xor(pp, 4);
            pp += __shfl_xor(pp, 2);  pp += __shfl_xor(pp, 1);
            p = p / fmaxf(sqrtf(pp), 1e-12f);
            if (idx == mn) idx = 0x7fffffff;
        }
    } else {
        // exact fallback (statistically never at N/C=8): full ballot scan
        for (int ii = 0; ii < N; ii += 64) {
            unsigned long long m = __ballot(tgt[ii + lane] == c);
            while (m) {
                int j = __ffsll(m) - 1;
                m &= (m - 1);
                float s = bf2f(xnb[(size_t)(ii + j) * D + e]);
                p = fmaf(0.05f, s, 0.95f * p);
                float pp = p * p;
                pp += __shfl_xor(pp, 16); pp += __shfl_xor(pp, 8); pp += __shfl_xor(pp, 4);
                pp += __shfl_xor(pp, 2);  pp += __shfl_xor(pp, 1);
                p = p / fmaxf(sqrtf(pp), 1e-12f);
            }
        }
    }

    float pp = p * p;
    pp += __shfl_xor(pp, 16); pp += __shfl_xor(pp, 8); pp += __shfl_xor(pp, 4);
    pp += __shfl_xor(pp, 2);  pp += __shfl_xor(pp, 1);
    float pn = p / fmaxf(sqrtf(pp), 1e-8f);
    float kap = fmaxf(kw[c], 0.0f);
    if (lane < D) qb[(size_t)c * D + e] = f2bf(kap * pn);
    if (lane == 0) {
        // log C_d(kap), cancellation-free rearrangement
        float nu = 0.5f * dval - 1.0f;
        float z  = kap / nu, z2 = z * z;
        float sq = sqrtf(1.0f + z2);
        float t  = 1.0f / sq;
        float u1 = (3.0f * t - 5.0f * t * t * t) * (1.0f / 24.0f);
        float lw = dval * (-0.918938533204672742f)
                 + nu * (logf(nu) + log1pf(sq) - sq)
                 + 0.5f * logf(6.2831853071795864f * nu)
                 + 0.25f * log1pf(z2)
                 - log1pf(u1 / nu);
        w[c] = __expf(lw);
    }
}

// ---- K3: MFMA cos -> fused w*exp -> per-sample partial row-sums ----
__global__ void __launch_bounds__(256, 8)
k_slice(const unsigned short* __restrict__ xnb, const unsigned short* __restrict__ qb,
        const float* __restrict__ w, float* __restrict__ Sp, int N, int C) {
    int gw = (blockIdx.x * blockDim.x + threadIdx.x) >> 6;   // 8192 waves
    int lane = threadIdx.x & 63;
    int sl = gw >> 9;          // 0..15  (class slice)
    int sw = gw & 511;         // 0..511 (sample group of 32)
    int s0 = sw * 32;
    int m = lane & 15, kg = lane >> 4, k0 = kg * 8;

    short8v a0 = *(const short8v*)(xnb + (size_t)(s0 + m) * D + k0);
    short8v a1 = *(const short8v*)(xnb + (size_t)(s0 + 16 + m) * D + k0);

    float4v z = {0.f, 0.f, 0.f, 0.f};
    float4v sa0 = z, sa1 = z;
    int ctbase = sl * 8;
#pragma unroll
    for (int j = 0; j < 8; ++j) {
        int c0 = (ctbase + j) * 16;
        short8v b = *(const short8v*)(qb + (size_t)(c0 + m) * D + k0);
        float wl = w[c0 + m];
        float4v acc0 = __builtin_amdgcn_mfma_f32_16x16x32_bf16(a0, b, z, 0, 0, 0);
        float4v acc1 = __builtin_amdgcn_mfma_f32_16x16x32_bf16(a1, b, z, 0, 0, 0);
#pragma unroll
        for (int r = 0; r < 4; ++r) {
            sa0[r] = fmaf(wl, __expf(acc0[r]), sa0[r]);
            sa1[r] = fmaf(wl, __expf(acc1[r]), sa1[r]);
        }
    }
#pragma unroll
    for (int off = 1; off < 16; off <<= 1) {
#pragma unroll
        for (int r = 0; r < 4; ++r) {
            sa0[r] += __shfl_xor(sa0[r], off);
            sa1[r] += __shfl_xor(sa1[r], off);
        }
    }
    if (m == 0) {
#pragma unroll
        for (int r = 0; r < 4; ++r) {
            int sA = s0 + kg * 4 + r;
            Sp[(size_t)sA * NS2 + sl] = sa0[r];
            Sp[(size_t)(sA + 16) * NS2 + sl] = sa1[r];
        }
    }
}

// ---- K4: per-sample NLL + block partials + last-block final reduce ----
__global__ void k_nll(const unsigned short* __restrict__ xnb, const unsigned short* __restrict__ qb,
                      const int* __restrict__ tgt, const float* __restrict__ w,
                      const float* __restrict__ Sp, float* __restrict__ part,
                      int* __restrict__ done, float* __restrict__ out, int N, int nblk) {
    int i = blockIdx.x * blockDim.x + threadIdx.x;
    float val = 0.0f;
    if (i < N) {
        float S = 0.f;
        const float4* sp = (const float4*)(Sp + (size_t)i * NS2);
#pragma unroll
        for (int j = 0; j < NS2 / 4; ++j) { float4 v = sp[j]; S += (v.x + v.y) + (v.z + v.w); }
        int t = tgt[i];
        float d = 0.f;
        const ushort4* xa = (const ushort4*)(xnb + (size_t)i * D);
        const ushort4* qa = (const ushort4*)(qb + (size_t)t * D);
#pragma unroll
        for (int j = 0; j < D / 4; ++j) {
            ushort4 xv = xa[j], qv = qa[j];
            d = fmaf(bf2f(xv.x), bf2f(qv.x), d);
            d = fmaf(bf2f(xv.y), bf2f(qv.y), d);
            d = fmaf(bf2f(xv.z), bf2f(qv.z), d);
            d = fmaf(bf2f(xv.w), bf2f(qv.w), d);
        }
        float num = w[t] * __expf(d);
        val = logf(num / S + 1e-6f);
    }
    __shared__ float red[4];
    __shared__ int lastflag;
    val += __shfl_xor(val, 32); val += __shfl_xor(val, 16); val += __shfl_xor(val, 8);
    val += __shfl_xor(val, 4);  val += __shfl_xor(val, 2);  val += __shfl_xor(val, 1);
    if ((threadIdx.x & 63) == 0) red[threadIdx.x >> 6] = val;
    __syncthreads();
    if (threadIdx.x == 0) {
        float bp = (red[0] + red[1]) + (red[2] + red[3]);
        atomicExch((unsigned int*)&part[blockIdx.x], __float_as_uint(bp));  // coherent publish
        __threadfence();
        int old = atomicAdd(done, 1);
        lastflag = (old == nblk - 1) ? 1 : 0;
    }
    __syncthreads();
    if (lastflag && threadIdx.x < 64) {
        __threadfence();
        unsigned int u = atomicAdd((unsigned int*)&part[threadIdx.x], 0u);  // coherent read
        float v = (threadIdx.x < nblk) ? __uint_as_float(u) : 0.f;
        v += __shfl_xor(v, 32); v += __shfl_xor(v, 16); v += __shfl_xor(v, 8);
        v += __shfl_xor(v, 4);  v += __shfl_xor(v, 2);  v += __shfl_xor(v, 1);
        if (threadIdx.x == 0) out[0] = -v / (float)N;
    }
}

extern "C" void kernel_launch(void* const* d_in, const int* in_sizes, int n_in,
                              void* d_out, int out_size, void* d_ws, size_t ws_size,
                              hipStream_t stream) {
    const float* x    = (const float*)d_in[0];   // [N, D]
    const float* kw   = (const float*)d_in[1];   // [C]
    const float* p_in = (const float*)d_in[2];   // [C, D]
    const int*   tgt  = (const int*)d_in[3];     // [N]
    int C = in_sizes[1];
    int N = in_sizes[3];
    float dval = (float)(in_sizes[2] / C);       // == 32

    unsigned short* xnb = (unsigned short*)d_ws;           // N*D bf16   (1 MB)
    unsigned short* qb  = xnb + (size_t)N * D;             // C*D bf16   (128 KB)
    float* w    = (float*)(qb + (size_t)C * D);            // C f32
    float* Sp   = w + C;                                   // N*NS2 f32  (1 MB)
    float* part = Sp + (size_t)N * NS2;                    // 64 f32
    int* cnt    = (int*)(part + 64);                       // C ints   } zeroed
    int* done   = cnt + C;                                 // 1 int    } together
    int* list2d = done + 1;                                // C*CAP ints (512 KB)
    (void)n_in; (void)out_size; (void)ws_size;

    int nblk = N / 256;   // 64

    // node 1: zero cnt + done (graph-capture-legal async memset)
    hipMemsetAsync(cnt, 0, (size_t)(C + 1) * sizeof(int), stream);
    // node 2: normalize + bf16 + bucket scatter
    k_normalize<<<(N * 8 + 255) / 256, 256, 0, stream>>>(x, tgt, xnb, cnt, list2d, N);
    // node 3: per-class EMA chains -> qb, w
    k_proto<<<(C * 64 + 255) / 256, 256, 0, stream>>>(xnb, tgt, list2d, cnt, p_in, kw, qb, w, N, C, dval);
    // node 4: MFMA + fused exp/rowsum partials (8192 waves)
    k_slice<<<((N / 32) * NS2) / 4, 256, 0, stream>>>(xnb, qb, w, Sp, N, C);
    // node 5: per-sample NLL + partials + last-block final reduce
    k_nll<<<nblk, 256, 0, stream>>>(xnb, qb, tgt, w, Sp, part, done, (float*)d_out, N, nblk);
}